// Round 2
// baseline (271.792 us; speedup 1.0000x reference)
//
#include <hip/hip_runtime.h>

#define BB 2
#define SS 2048
#define EE 768
#define HH 12
#define DKK 64

typedef _Float16 h16;
typedef _Float16 half8 __attribute__((ext_vector_type(8)));
typedef _Float16 h16x4 __attribute__((ext_vector_type(4)));
typedef float f32x4 __attribute__((ext_vector_type(4)));

// ---------------- mask packing: int32 [S,S] -> 1 bit, word = 32 cols ----------------
__global__ void pack_mask_k(const int* __restrict__ mask, unsigned* __restrict__ mp) {
    int idx = blockIdx.x * 256 + threadIdx.x;      // 0 .. S*S/32-1
    int base = idx * 32;
    const int4* m4 = (const int4*)(mask + base);
    unsigned w = 0;
#pragma unroll
    for (int i = 0; i < 8; ++i) {
        int4 v = m4[i];
        if (v.x) w |= 1u << (i * 4 + 0);
        if (v.y) w |= 1u << (i * 4 + 1);
        if (v.z) w |= 1u << (i * 4 + 2);
        if (v.w) w |= 1u << (i * 4 + 3);
    }
    mp[idx] = w;
}

// ---------------- projection GEMM: k/q row-major [b,h,s,d]; v TRANSPOSED [b,h,d,s] ----------------
__launch_bounds__(256)
__global__ void proj_gemm_k(const float* __restrict__ srcK, const float* __restrict__ srcQ,
                            const float* __restrict__ srcV, const float* __restrict__ Wk,
                            const float* __restrict__ bk,
                            h16* __restrict__ kh, h16* __restrict__ qh, h16* __restrict__ vtp) {
    __shared__ h16 As[128 * 64];
    __shared__ h16 Bs[128 * 64];
    const int z = blockIdx.z;
    const float* src = (z == 0) ? srcK : ((z == 1) ? srcQ : srcV);
    const int n0 = blockIdx.x * 128, m0 = blockIdx.y * 128;
    const int tid = threadIdx.x, lane = tid & 63, wid = tid >> 6;
    const int wr = wid >> 1, wc = wid & 1;
    f32x4 acc[4][4] = {};

    for (int k0 = 0; k0 < EE; k0 += 64) {
#pragma unroll
        for (int it = 0; it < 4; ++it) {
            int e8 = it * 256 + tid;          // 0..1023 granules of 8 elems
            int row = e8 >> 3, g = e8 & 7;
            const float* pa = src + (m0 + row) * EE + k0 + g * 8;
            const float* pb = Wk + (n0 + row) * EE + k0 + g * 8;
            float4 a0 = *(const float4*)pa, a1 = *(const float4*)(pa + 4);
            float4 b0 = *(const float4*)pb, b1 = *(const float4*)(pb + 4);
            half8 ha = {(h16)a0.x, (h16)a0.y, (h16)a0.z, (h16)a0.w,
                        (h16)a1.x, (h16)a1.y, (h16)a1.z, (h16)a1.w};
            half8 hb = {(h16)b0.x, (h16)b0.y, (h16)b0.z, (h16)b0.w,
                        (h16)b1.x, (h16)b1.y, (h16)b1.z, (h16)b1.w};
            int sw = (g ^ (row & 7)) << 4;
            *(half8*)((char*)As + row * 128 + sw) = ha;
            *(half8*)((char*)Bs + row * 128 + sw) = hb;
        }
        __syncthreads();
#pragma unroll
        for (int ks = 0; ks < 2; ++ks) {
            half8 a[4], b[4];
#pragma unroll
            for (int rf = 0; rf < 4; ++rf) {
                int row = wr * 64 + rf * 16 + (lane & 15);
                int g = (ks * 4 + (lane >> 4)) ^ (row & 7);
                a[rf] = *(const half8*)((const char*)As + row * 128 + (g << 4));
            }
#pragma unroll
            for (int cf = 0; cf < 4; ++cf) {
                int row = wc * 64 + cf * 16 + (lane & 15);
                int g = (ks * 4 + (lane >> 4)) ^ (row & 7);
                b[cf] = *(const half8*)((const char*)Bs + row * 128 + (g << 4));
            }
#pragma unroll
            for (int rf = 0; rf < 4; ++rf)
#pragma unroll
                for (int cf = 0; cf < 4; ++cf)
                    acc[rf][cf] = __builtin_amdgcn_mfma_f32_16x16x32_f16(a[rf], b[cf], acc[rf][cf], 0, 0, 0);
        }
        __syncthreads();
    }
    if (z == 2) {
        // V: write transposed vt[(b*H+h)*64 + d][s], 4 consecutive s packed
#pragma unroll
        for (int rf = 0; rf < 4; ++rf)
#pragma unroll
            for (int cf = 0; cf < 4; ++cf) {
                int n = n0 + wc * 64 + cf * 16 + (lane & 15);
                float bias = bk[n];
                int h = n >> 6, d = n & 63;
                int mb = m0 + wr * 64 + rf * 16 + (lane >> 4) * 4;
                int b = mb >> 11, s = mb & 2047;
                h16x4 pv = {(h16)(acc[rf][cf][0] + bias), (h16)(acc[rf][cf][1] + bias),
                            (h16)(acc[rf][cf][2] + bias), (h16)(acc[rf][cf][3] + bias)};
                *(h16x4*)(vtp + ((long)((b * HH + h) * 64 + d)) * SS + s) = pv;
            }
    } else {
        h16* dst = (z == 0) ? kh : qh;
#pragma unroll
        for (int rf = 0; rf < 4; ++rf)
#pragma unroll
            for (int cf = 0; cf < 4; ++cf) {
                int n = n0 + wc * 64 + cf * 16 + (lane & 15);
                float bias = bk[n];
                int h = n >> 6, d = n & 63;
#pragma unroll
                for (int j = 0; j < 4; ++j) {
                    int m = m0 + wr * 64 + rf * 16 + (lane >> 4) * 4 + j;
                    int b = m >> 11, s = m & 2047;
                    dst[(((long)(b * HH + h) * SS + s) << 6) + d] = (h16)(acc[rf][cf][j] + bias);
                }
            }
    }
}

// ---------------- flash attention: 1 wave per 16 q-rows, no barriers ----------------
// swapped QK^T: s[cf][j] = S^T[kv = cf*16+g*4+j][q = lane&15]
__launch_bounds__(64)
__global__ void attn_k(const h16* __restrict__ qh, const h16* __restrict__ kh,
                       const h16* __restrict__ vt, const unsigned long long* __restrict__ mp,
                       h16* __restrict__ xh) {
    __shared__ char Ps[2048];                  // P^T [q=16][kv=64] f16, 16B-granule XOR swizzle
    const int lane = threadIdx.x;
    const int l = lane & 15, g = lane >> 4;
    const int q0 = blockIdx.x * 16;
    const int bh = blockIdx.y;
    const long base = (long)bh * SS * DKK;

    half8 qf0, qf1;
    {
        const h16* qp = qh + base + (long)(q0 + l) * DKK + g * 8;
        qf0 = *(const half8*)qp;
        qf1 = *(const half8*)(qp + 32);
    }
    const unsigned long long* mrow = mp + (long)(q0 + l) * (SS / 64);

    f32x4 o[4] = {};
    float m2 = -INFINITY, lsum = 0.f;
    const float K2 = 8.0f * 1.44269504f;       // sqrt(dk) * log2(e)  (source multiplies!)
    const float C2 = 1e-6f * 1.44269504f;      // masked value in log2 domain
    const float THR = 11.0f;

    for (int kv0 = 0; kv0 < SS; kv0 += 64) {
        // ---- QK^T (K as A-operand, Q as B) ----
        f32x4 s[4] = {};
        const h16* kp = kh + base + (long)(kv0 + l) * DKK + g * 8;
#pragma unroll
        for (int cf = 0; cf < 4; ++cf) {
            half8 ka = *(const half8*)(kp + cf * (16 * DKK));
            half8 kb = *(const half8*)(kp + cf * (16 * DKK) + 32);
            s[cf] = __builtin_amdgcn_mfma_f32_16x16x32_f16(ka, qf0, s[cf], 0, 0, 0);
            s[cf] = __builtin_amdgcn_mfma_f32_16x16x32_f16(kb, qf1, s[cf], 0, 0, 0);
        }
        // ---- V fragments issued early; latency hides under softmax ----
        half8 vr[2][4];
        const h16* vp = vt + base + (long)l * SS + kv0 + g * 8;
#pragma unroll
        for (int ks = 0; ks < 2; ++ks)
#pragma unroll
            for (int df = 0; df < 4; ++df)
                vr[ks][df] = *(const half8*)(vp + (long)df * (16 * SS) + ks * 32);

        // ---- mask + scale into exp2 domain ----
        unsigned long long mw = mrow[kv0 >> 6];
        unsigned w0 = (unsigned)mw, w1 = (unsigned)(mw >> 32);
#pragma unroll
        for (int cf = 0; cf < 4; ++cf) {
            unsigned wc = (cf & 2) ? w1 : w0;
#pragma unroll
            for (int j = 0; j < 4; ++j) {
                unsigned sh = ((cf & 1) << 4) + g * 4 + j;
                s[cf][j] = ((wc >> sh) & 1u) ? s[cf][j] * K2 : C2;
            }
        }
        // ---- online softmax (per-lane q; reduce over 16 regs + 2 shfl) ----
        float pmax = s[0][0];
#pragma unroll
        for (int cf = 0; cf < 4; ++cf)
#pragma unroll
            for (int j = 0; j < 4; ++j) pmax = fmaxf(pmax, s[cf][j]);
        pmax = fmaxf(pmax, __shfl_xor(pmax, 16));
        pmax = fmaxf(pmax, __shfl_xor(pmax, 32));
        if (!__all(pmax <= m2 + THR)) {        // defer-max (T13)
            float mnew = fmaxf(m2, pmax);
            float alpha = __builtin_amdgcn_exp2f(m2 - mnew);
#pragma unroll
            for (int df = 0; df < 4; ++df)
#pragma unroll
                for (int j = 0; j < 4; ++j) o[df][j] *= alpha;
            lsum *= alpha;
            m2 = mnew;
        }
        float rs = 0.f;
#pragma unroll
        for (int cf = 0; cf < 4; ++cf)
#pragma unroll
            for (int j = 0; j < 4; ++j) {
                float p = __builtin_amdgcn_exp2f(s[cf][j] - m2);
                s[cf][j] = p;
                rs += p;
            }
        rs += __shfl_xor(rs, 16);
        rs += __shfl_xor(rs, 32);
        lsum += rs;
        // ---- P^T -> per-wave LDS [q][kv] (no barrier needed) ----
#pragma unroll
        for (int cf = 0; cf < 4; ++cf)
#pragma unroll
            for (int j = 0; j < 4; ++j) {
                int kv = cf * 16 + g * 4 + j;
                int byt = l * 128 + ((((kv >> 3) ^ (l & 7)) << 4) | ((kv & 7) * 2));
                *(h16*)(Ps + byt) = (h16)s[cf][j];
            }
        // ---- O^T += V^T · P^T ----
#pragma unroll
        for (int ks = 0; ks < 2; ++ks) {
            int gr = (ks * 4 + g) ^ (l & 7);
            half8 pf = *(const half8*)(Ps + l * 128 + gr * 16);
#pragma unroll
            for (int df = 0; df < 4; ++df)
                o[df] = __builtin_amdgcn_mfma_f32_16x16x32_f16(vr[ks][df], pf, o[df], 0, 0, 0);
        }
    }
    // epilogue: lane owns q = q0+l; o[df][j] = O^T[d=df*16+g*4+j][q]
    float inv = 1.0f / lsum;
    int b = bh / HH, h = bh % HH;
    h16* xp = xh + (long)(b * SS + q0 + l) * EE + h * 64 + g * 4;
#pragma unroll
    for (int df = 0; df < 4; ++df) {
        h16x4 v4 = {(h16)(o[df][0] * inv), (h16)(o[df][1] * inv),
                    (h16)(o[df][2] * inv), (h16)(o[df][3] * inv)};
        *(h16x4*)(xp + df * 16) = v4;
    }
}

// ---------------- output GEMM: out = x @ Wo^T + bo (fp32 out) ----------------
__launch_bounds__(256)
__global__ void out_gemm_k(const h16* __restrict__ xh, const float* __restrict__ Wo,
                           const float* __restrict__ bo, float* __restrict__ out) {
    __shared__ h16 As[128 * 64];
    __shared__ h16 Bs[128 * 64];
    const int n0 = blockIdx.x * 128, m0 = blockIdx.y * 128;
    const int tid = threadIdx.x, lane = tid & 63, wid = tid >> 6;
    const int wr = wid >> 1, wc = wid & 1;
    f32x4 acc[4][4] = {};

    for (int k0 = 0; k0 < EE; k0 += 64) {
#pragma unroll
        for (int it = 0; it < 4; ++it) {
            int e8 = it * 256 + tid;
            int row = e8 >> 3, g = e8 & 7;
            half8 ha = *(const half8*)(xh + (m0 + row) * EE + k0 + g * 8);
            const float* pb = Wo + (n0 + row) * EE + k0 + g * 8;
            float4 b0 = *(const float4*)pb, b1 = *(const float4*)(pb + 4);
            half8 hb = {(h16)b0.x, (h16)b0.y, (h16)b0.z, (h16)b0.w,
                        (h16)b1.x, (h16)b1.y, (h16)b1.z, (h16)b1.w};
            int sw = (g ^ (row & 7)) << 4;
            *(half8*)((char*)As + row * 128 + sw) = ha;
            *(half8*)((char*)Bs + row * 128 + sw) = hb;
        }
        __syncthreads();
#pragma unroll
        for (int ks = 0; ks < 2; ++ks) {
            half8 a[4], b[4];
#pragma unroll
            for (int rf = 0; rf < 4; ++rf) {
                int row = wr * 64 + rf * 16 + (lane & 15);
                int g = (ks * 4 + (lane >> 4)) ^ (row & 7);
                a[rf] = *(const half8*)((const char*)As + row * 128 + (g << 4));
            }
#pragma unroll
            for (int cf = 0; cf < 4; ++cf) {
                int row = wc * 64 + cf * 16 + (lane & 15);
                int g = (ks * 4 + (lane >> 4)) ^ (row & 7);
                b[cf] = *(const half8*)((const char*)Bs + row * 128 + (g << 4));
            }
#pragma unroll
            for (int rf = 0; rf < 4; ++rf)
#pragma unroll
                for (int cf = 0; cf < 4; ++cf)
                    acc[rf][cf] = __builtin_amdgcn_mfma_f32_16x16x32_f16(a[rf], b[cf], acc[rf][cf], 0, 0, 0);
        }
        __syncthreads();
    }
#pragma unroll
    for (int rf = 0; rf < 4; ++rf)
#pragma unroll
        for (int cf = 0; cf < 4; ++cf) {
            int n = n0 + wc * 64 + cf * 16 + (lane & 15);
            float bias = bo[n];
#pragma unroll
            for (int j = 0; j < 4; ++j) {
                int m = m0 + wr * 64 + rf * 16 + (lane >> 4) * 4 + j;
                out[(long)m * EE + n] = acc[rf][cf][j] + bias;
            }
        }
}

extern "C" void kernel_launch(void* const* d_in, const int* in_sizes, int n_in,
                              void* d_out, int out_size, void* d_ws, size_t ws_size,
                              hipStream_t stream) {
    const float* key   = (const float*)d_in[0];
    const float* query = (const float*)d_in[1];
    const float* value = (const float*)d_in[2];
    const int*   mask  = (const int*)d_in[3];
    const float* Wk    = (const float*)d_in[4];
    const float* bk    = (const float*)d_in[5];
    const float* Wo    = (const float*)d_in[6];
    const float* bo    = (const float*)d_in[7];

    char* ws = (char*)d_ws;
    h16* qh = (h16*)(ws + 0);
    h16* kh = (h16*)(ws + 6291456);
    h16* vt = (h16*)(ws + 12582912);
    h16* xh = (h16*)(ws + 18874368);
    unsigned* mp = (unsigned*)(ws + 25165824);
    float* out = (float*)d_out;

    hipLaunchKernelGGL(pack_mask_k, dim3(SS * SS / 32 / 256), dim3(256), 0, stream, mask, mp);
    hipLaunchKernelGGL(proj_gemm_k, dim3(EE / 128, BB * SS / 128, 3), dim3(256), 0, stream,
                       key, query, value, Wk, bk, kh, qh, vt);
    hipLaunchKernelGGL(attn_k, dim3(SS / 16, BB * HH), dim3(64), 0, stream,
                       qh, kh, vt, (const unsigned long long*)mp, xh);
    hipLaunchKernelGGL(out_gemm_k, dim3(EE / 128, BB * SS / 128), dim3(256), 0, stream, xh, Wo, bo, out);
}